// Round 3
// baseline (1327.686 us; speedup 1.0000x reference)
//
#include <hip/hip_runtime.h>

#define N_NODES 100000
#define N_EDGES 3200000
#define IN_DIM 64
#define HID_DIM 128
#define OUT_DIM 2
#define NB_SCAN 391   // ceil(N_NODES / 256)
#define NBUCK 782     // ceil(N_NODES / 128): dst-bucket = dst >> 7

// ---------------------------------------------------------------------------
// K1: int in-degree histogram (real edges only; self-loop folded in as +1 later)
__global__ __launch_bounds__(256) void deg_count_kernel(const int* __restrict__ dst,
                                                        int* __restrict__ degi) {
    int e = blockIdx.x * 256 + threadIdx.x;
    if (e < N_EDGES) atomicAdd(&degi[dst[e]], 1);
}

// K2: per-256-block sums of degi -> partial[NB_SCAN]
__global__ __launch_bounds__(256) void blocksum_kernel(const int* __restrict__ degi,
                                                       int* __restrict__ partial) {
    __shared__ int s[256];
    const int tid = threadIdx.x;
    const int i = blockIdx.x * 256 + tid;
    s[tid] = (i < N_NODES) ? degi[i] : 0;
    __syncthreads();
    #pragma unroll
    for (int off = 128; off > 0; off >>= 1) {
        if (tid < off) s[tid] += s[tid + off];
        __syncthreads();
    }
    if (tid == 0) partial[blockIdx.x] = s[0];
}

// K3: exclusive scan of partial[NB_SCAN] in one 512-thread block
__global__ __launch_bounds__(512) void scan_partial_kernel(int* __restrict__ partial) {
    __shared__ int s[512];
    const int tid = threadIdx.x;
    const int v = (tid < NB_SCAN) ? partial[tid] : 0;
    s[tid] = v;
    __syncthreads();
    for (int off = 1; off < 512; off <<= 1) {
        int t = (tid >= off) ? s[tid - off] : 0;
        __syncthreads();
        s[tid] += t;
        __syncthreads();
    }
    if (tid < NB_SCAN) partial[tid] = s[tid] - v;   // exclusive
}

// K4: local inclusive scan + block offset -> row_ptr, cursor, bucket cursors; also dinv
__global__ __launch_bounds__(256) void writeptr_kernel(const int* __restrict__ degi,
                                                       const int* __restrict__ partial,
                                                       int* __restrict__ row_ptr,
                                                       int* __restrict__ cursor,
                                                       int* __restrict__ bcur,
                                                       float* __restrict__ dinv) {
    __shared__ int s[256];
    const int tid = threadIdx.x;
    const int i = blockIdx.x * 256 + tid;
    const int v = (i < N_NODES) ? degi[i] : 0;
    s[tid] = v;
    __syncthreads();
    for (int off = 1; off < 256; off <<= 1) {
        int t = (tid >= off) ? s[tid - off] : 0;
        __syncthreads();
        s[tid] += t;
        __syncthreads();
    }
    if (i < N_NODES) {
        const int start = partial[blockIdx.x] + s[tid] - v;   // exclusive global
        row_ptr[i] = start;
        cursor[i]  = start;
        dinv[i]    = rsqrtf((float)v + 1.0f);
        if ((i & 127) == 0) bcur[i >> 7] = start;             // bucket b starts at node 128b
        if (i == N_NODES - 1) row_ptr[N_NODES] = start + v;
    }
}

// K5a: bucket scatter — group edges by 128-node dst-bucket into tmp (int2 = src,dst).
// 782 sequential write streams -> ~1x write amplification (vs 15x for direct fill).
__global__ __launch_bounds__(256) void bucket_kernel(const int* __restrict__ ei,
                                                     int* __restrict__ bcur,
                                                     int2* __restrict__ tmp) {
    int e = blockIdx.x * 256 + threadIdx.x;
    if (e < N_EDGES) {
        const int s = ei[e];
        const int d = ei[N_EDGES + e];
        const int pos = atomicAdd(&bcur[d >> 7], 1);
        tmp[pos] = make_int2(s, d);
    }
}

// K5b: localized CSR fill — tmp is bucket-grouped, so cursor atomics hit a 512B
// window and col writes a ~16KB window per run: L2-resident, amp ~1x.
__global__ __launch_bounds__(256) void fill2_kernel(const int2* __restrict__ tmp,
                                                    int* __restrict__ cursor,
                                                    int* __restrict__ col) {
    int e = blockIdx.x * 256 + threadIdx.x;
    if (e < N_EDGES) {
        const int2 sd = tmp[e];
        const int pos = atomicAdd(&cursor[sd.y], 1);
        col[pos] = sd.x;
    }
}

// K6: g = (x @ W_gcn) * dinv[row].  W (64x128 = 32KB) staged in LDS.
#define GEMM_NPB 8
__global__ __launch_bounds__(256) void gemm_kernel(const float* __restrict__ x,
                                                   const float* __restrict__ W,
                                                   const float* __restrict__ dinv,
                                                   float* __restrict__ g) {
    __shared__ float4 Ws[IN_DIM * HID_DIM / 4];       // 32 KB
    __shared__ float  xs[GEMM_NPB * IN_DIM];          // 2 KB
    const int tid = threadIdx.x;

    const float4* W4 = (const float4*)W;
    #pragma unroll
    for (int i = tid; i < IN_DIM * HID_DIM / 4; i += 256) Ws[i] = W4[i];

    const int node0 = blockIdx.x * GEMM_NPB;
    const float4* x4 = (const float4*)(x + (size_t)node0 * IN_DIM);
    for (int i = tid; i < GEMM_NPB * IN_DIM / 4; i += 256) ((float4*)xs)[i] = x4[i];
    __syncthreads();

    const int jq = tid & 31;
    const int nl = tid >> 5;
    const float* xrow = xs + nl * IN_DIM;

    float4 acc = {0.f, 0.f, 0.f, 0.f};
    #pragma unroll
    for (int k = 0; k < IN_DIM; ++k) {
        const float  xv = xrow[k];
        const float4 wv = Ws[k * 32 + jq];
        acc.x += xv * wv.x; acc.y += xv * wv.y;
        acc.z += xv * wv.z; acc.w += xv * wv.w;
    }
    const int node = node0 + nl;
    const float dv = dinv[node];
    acc.x *= dv; acc.y *= dv; acc.z *= dv; acc.w *= dv;
    ((float4*)g)[(size_t)node * 32 + jq] = acc;
}

// K7: fused gather + epilogue. 32 lanes per node; lane l holds float4 cols 4l..4l+3.
__global__ __launch_bounds__(256) void gather_kernel(const int* __restrict__ row_ptr,
                                                     const int* __restrict__ col,
                                                     const float* __restrict__ g,
                                                     const float* __restrict__ dinv,
                                                     const float* __restrict__ b_gcn,
                                                     const float* __restrict__ W_lin,
                                                     const float* __restrict__ b_lin,
                                                     float* __restrict__ out) {
    const int t    = blockIdx.x * 256 + threadIdx.x;
    const int n    = t >> 5;
    const int lane = t & 31;
    if (n >= N_NODES) return;

    const float4* g4 = (const float4*)g;
    float4 acc = g4[(size_t)n * 32 + lane];           // self-loop message
    const int beg = row_ptr[n];
    const int end = row_ptr[n + 1];

    for (int k = beg; k < end; k += 32) {
        const int m = end - k;
        const int sc = (lane < m) ? col[k + lane] : 0;   // 32 cols, coalesced
        const int lim = m < 32 ? m : 32;
        for (int j = 0; j < lim; ++j) {
            const int s = __shfl(sc, j, 32);
            const float4 v = g4[(size_t)s * 32 + lane];  // 512B coalesced per group
            acc.x += v.x; acc.y += v.y; acc.z += v.z; acc.w += v.w;
        }
    }

    const float dv = dinv[n];
    const float4 bg = ((const float4*)b_gcn)[lane];
    float4 v;
    v.x = fmaxf(acc.x * dv + bg.x, 0.f);
    v.y = fmaxf(acc.y * dv + bg.y, 0.f);
    v.z = fmaxf(acc.z * dv + bg.z, 0.f);
    v.w = fmaxf(acc.w * dv + bg.w, 0.f);

    const int c = lane * 4;
    float o0 = v.x * W_lin[(c+0)*2] + v.y * W_lin[(c+1)*2] + v.z * W_lin[(c+2)*2] + v.w * W_lin[(c+3)*2];
    float o1 = v.x * W_lin[(c+0)*2+1] + v.y * W_lin[(c+1)*2+1] + v.z * W_lin[(c+2)*2+1] + v.w * W_lin[(c+3)*2+1];

    #pragma unroll
    for (int off = 16; off > 0; off >>= 1) {
        o0 += __shfl_down(o0, off, 32);
        o1 += __shfl_down(o1, off, 32);
    }
    if (lane == 0) {
        out[(size_t)n * 2 + 0] = o0 + b_lin[0];
        out[(size_t)n * 2 + 1] = o1 + b_lin[1];
    }
}

extern "C" void kernel_launch(void* const* d_in, const int* in_sizes, int n_in,
                              void* d_out, int out_size, void* d_ws, size_t ws_size,
                              hipStream_t stream) {
    const float* x     = (const float*)d_in[0];
    const int*   ei    = (const int*)  d_in[1];   // [2, E]: row 0 = src, row 1 = dst
    const float* W_gcn = (const float*)d_in[2];
    const float* b_gcn = (const float*)d_in[3];
    const float* W_lin = (const float*)d_in[4];
    const float* b_lin = (const float*)d_in[5];
    float* out = (float*)d_out;

    // workspace layout (4-byte elems, g first for float4 alignment):
    // g[N*128] | col[E] | row_ptr[N+1] | cursor[N] | degi[N] | dinv[N] | partial[512] | bcur[NBUCK]
    // tmp (int2[E], 25.6 MB) aliases the g region (51.2 MB) — consumed before gemm writes g.
    float* g       = (float*)d_ws;
    int*   col     = (int*)(g + (size_t)N_NODES * HID_DIM);
    int*   row_ptr = col + N_EDGES;
    int*   cursor  = row_ptr + (N_NODES + 1);
    int*   degi    = cursor + N_NODES;
    float* dinv    = (float*)(degi + N_NODES);
    int*   partial = (int*)(dinv + N_NODES);
    int*   bcur    = partial + 512;
    int2*  tmp     = (int2*)g;

    hipMemsetAsync(degi, 0, N_NODES * sizeof(int), stream);

    deg_count_kernel<<<(N_EDGES + 255) / 256, 256, 0, stream>>>(ei + N_EDGES, degi);
    blocksum_kernel<<<NB_SCAN, 256, 0, stream>>>(degi, partial);
    scan_partial_kernel<<<1, 512, 0, stream>>>(partial);
    writeptr_kernel<<<NB_SCAN, 256, 0, stream>>>(degi, partial, row_ptr, cursor, bcur, dinv);
    bucket_kernel<<<(N_EDGES + 255) / 256, 256, 0, stream>>>(ei, bcur, tmp);
    fill2_kernel<<<(N_EDGES + 255) / 256, 256, 0, stream>>>(tmp, cursor, col);
    gemm_kernel<<<N_NODES / GEMM_NPB, 256, 0, stream>>>(x, W_gcn, dinv, g);   // overwrites tmp region
    gather_kernel<<<(N_NODES * 32 + 255) / 256, 256, 0, stream>>>(
        row_ptr, col, g, dinv, b_gcn, W_lin, b_lin, out);
}

// Round 4
// 535.926 us; speedup vs baseline: 2.4774x; 2.4774x over previous
//
#include <hip/hip_runtime.h>

#define N_NODES 100000
#define N_EDGES 3200000
#define IN_DIM 64
#define HID_DIM 128
#define OUT_DIM 2
#define NB_SCAN 391   // ceil(N_NODES / 256)

#define FP_PASSES 4
#define FP_NODES_PER_PASS 25000          // 4 * 25000 = 100000 exact
#define FP_EPT 4                         // edges per thread (int4 load of dst)
#define FP_BLOCKS_PER_PASS (N_EDGES / (256 * FP_EPT))   // 3125 exact

// ---------------------------------------------------------------------------
// K1: degree histogram + per-edge rank capture. rank = old count for dst, so
// (row_ptr[d] + rank) is a unique slot — fill needs no atomics at all.
// packed = src | (rank << 17): src < 2^17, rank (max in-deg ~70) << 2^15.
__global__ __launch_bounds__(256) void deg_rank_kernel(const int* __restrict__ ei,
                                                       int* __restrict__ degi,
                                                       int* __restrict__ packed) {
    int e = blockIdx.x * 256 + threadIdx.x;
    if (e < N_EDGES) {
        const int s = ei[e];
        const int d = ei[N_EDGES + e];
        const int r = atomicAdd(&degi[d], 1);   // 100k counters: ~32/addr contention, L2-resident
        packed[e] = s | (r << 17);              // sequential write
    }
}

// K2: per-256-block sums of degi -> partial[NB_SCAN]
__global__ __launch_bounds__(256) void blocksum_kernel(const int* __restrict__ degi,
                                                       int* __restrict__ partial) {
    __shared__ int s[256];
    const int tid = threadIdx.x;
    const int i = blockIdx.x * 256 + tid;
    s[tid] = (i < N_NODES) ? degi[i] : 0;
    __syncthreads();
    #pragma unroll
    for (int off = 128; off > 0; off >>= 1) {
        if (tid < off) s[tid] += s[tid + off];
        __syncthreads();
    }
    if (tid == 0) partial[blockIdx.x] = s[0];
}

// K3: exclusive scan of partial[NB_SCAN] in one 512-thread block
__global__ __launch_bounds__(512) void scan_partial_kernel(int* __restrict__ partial) {
    __shared__ int s[512];
    const int tid = threadIdx.x;
    const int v = (tid < NB_SCAN) ? partial[tid] : 0;
    s[tid] = v;
    __syncthreads();
    for (int off = 1; off < 512; off <<= 1) {
        int t = (tid >= off) ? s[tid - off] : 0;
        __syncthreads();
        s[tid] += t;
        __syncthreads();
    }
    if (tid < NB_SCAN) partial[tid] = s[tid] - v;   // exclusive
}

// K4: local scan + block offset -> row_ptr; also dinv
__global__ __launch_bounds__(256) void writeptr_kernel(const int* __restrict__ degi,
                                                       const int* __restrict__ partial,
                                                       int* __restrict__ row_ptr,
                                                       float* __restrict__ dinv) {
    __shared__ int s[256];
    const int tid = threadIdx.x;
    const int i = blockIdx.x * 256 + tid;
    const int v = (i < N_NODES) ? degi[i] : 0;
    s[tid] = v;
    __syncthreads();
    for (int off = 1; off < 256; off <<= 1) {
        int t = (tid >= off) ? s[tid - off] : 0;
        __syncthreads();
        s[tid] += t;
        __syncthreads();
    }
    if (i < N_NODES) {
        const int start = partial[blockIdx.x] + s[tid] - v;   // exclusive global
        row_ptr[i] = start;
        dinv[i]    = rsqrtf((float)v + 1.0f);
        if (i == N_NODES - 1) row_ptr[N_NODES] = start + v;
    }
}

// K5: atomic-free CSR fill, partitioned into FP_PASSES dst-range passes for
// write locality. Pass p (low block IDs first) writes only dst in
// [25000p, 25000(p+1)) -> col window ~3.2 MB, L2-resident. Slots disjoint.
__global__ __launch_bounds__(256) void fill_pass_kernel(const int* __restrict__ dst,
                                                        const int* __restrict__ packed,
                                                        const int* __restrict__ row_ptr,
                                                        int* __restrict__ col) {
    const int p  = blockIdx.x / FP_BLOCKS_PER_PASS;
    const int b  = blockIdx.x % FP_BLOCKS_PER_PASS;
    const int lo = p * FP_NODES_PER_PASS;
    const int hi = lo + FP_NODES_PER_PASS;
    const int e0 = (b * 256 + threadIdx.x) * FP_EPT;
    const int4 d4 = *(const int4*)(dst + e0);
    const int dd[4] = {d4.x, d4.y, d4.z, d4.w};
    #pragma unroll
    for (int i = 0; i < FP_EPT; ++i) {
        const int d = dd[i];
        if (d >= lo && d < hi) {
            const int pk = packed[e0 + i];
            col[row_ptr[d] + (pk >> 17)] = pk & 0x1FFFF;
        }
    }
}

// K6: g = (x @ W_gcn) * dinv[row].  W (64x128 = 32KB) staged in LDS.
#define GEMM_NPB 8
__global__ __launch_bounds__(256) void gemm_kernel(const float* __restrict__ x,
                                                   const float* __restrict__ W,
                                                   const float* __restrict__ dinv,
                                                   float* __restrict__ g) {
    __shared__ float4 Ws[IN_DIM * HID_DIM / 4];       // 32 KB
    __shared__ float  xs[GEMM_NPB * IN_DIM];          // 2 KB
    const int tid = threadIdx.x;

    const float4* W4 = (const float4*)W;
    #pragma unroll
    for (int i = tid; i < IN_DIM * HID_DIM / 4; i += 256) Ws[i] = W4[i];

    const int node0 = blockIdx.x * GEMM_NPB;
    const float4* x4 = (const float4*)(x + (size_t)node0 * IN_DIM);
    for (int i = tid; i < GEMM_NPB * IN_DIM / 4; i += 256) ((float4*)xs)[i] = x4[i];
    __syncthreads();

    const int jq = tid & 31;
    const int nl = tid >> 5;
    const float* xrow = xs + nl * IN_DIM;

    float4 acc = {0.f, 0.f, 0.f, 0.f};
    #pragma unroll
    for (int k = 0; k < IN_DIM; ++k) {
        const float  xv = xrow[k];
        const float4 wv = Ws[k * 32 + jq];
        acc.x += xv * wv.x; acc.y += xv * wv.y;
        acc.z += xv * wv.z; acc.w += xv * wv.w;
    }
    const int node = node0 + nl;
    const float dv = dinv[node];
    acc.x *= dv; acc.y *= dv; acc.z *= dv; acc.w *= dv;
    ((float4*)g)[(size_t)node * 32 + jq] = acc;
}

// K7: fused gather + epilogue. 32 lanes per node; lane l holds float4 cols 4l..4l+3.
__global__ __launch_bounds__(256) void gather_kernel(const int* __restrict__ row_ptr,
                                                     const int* __restrict__ col,
                                                     const float* __restrict__ g,
                                                     const float* __restrict__ dinv,
                                                     const float* __restrict__ b_gcn,
                                                     const float* __restrict__ W_lin,
                                                     const float* __restrict__ b_lin,
                                                     float* __restrict__ out) {
    const int t    = blockIdx.x * 256 + threadIdx.x;
    const int n    = t >> 5;
    const int lane = t & 31;
    if (n >= N_NODES) return;

    const float4* g4 = (const float4*)g;
    float4 acc = g4[(size_t)n * 32 + lane];           // self-loop message
    const int beg = row_ptr[n];
    const int end = row_ptr[n + 1];

    for (int k = beg; k < end; k += 32) {
        const int m = end - k;
        const int sc = (lane < m) ? col[k + lane] : 0;   // 32 cols, coalesced
        const int lim = m < 32 ? m : 32;
        for (int j = 0; j < lim; ++j) {
            const int s = __shfl(sc, j, 32);
            const float4 v = g4[(size_t)s * 32 + lane];  // 512B coalesced per group
            acc.x += v.x; acc.y += v.y; acc.z += v.z; acc.w += v.w;
        }
    }

    const float dv = dinv[n];
    const float4 bg = ((const float4*)b_gcn)[lane];
    float4 v;
    v.x = fmaxf(acc.x * dv + bg.x, 0.f);
    v.y = fmaxf(acc.y * dv + bg.y, 0.f);
    v.z = fmaxf(acc.z * dv + bg.z, 0.f);
    v.w = fmaxf(acc.w * dv + bg.w, 0.f);

    const int c = lane * 4;
    float o0 = v.x * W_lin[(c+0)*2] + v.y * W_lin[(c+1)*2] + v.z * W_lin[(c+2)*2] + v.w * W_lin[(c+3)*2];
    float o1 = v.x * W_lin[(c+0)*2+1] + v.y * W_lin[(c+1)*2+1] + v.z * W_lin[(c+2)*2+1] + v.w * W_lin[(c+3)*2+1];

    #pragma unroll
    for (int off = 16; off > 0; off >>= 1) {
        o0 += __shfl_down(o0, off, 32);
        o1 += __shfl_down(o1, off, 32);
    }
    if (lane == 0) {
        out[(size_t)n * 2 + 0] = o0 + b_lin[0];
        out[(size_t)n * 2 + 1] = o1 + b_lin[1];
    }
}

extern "C" void kernel_launch(void* const* d_in, const int* in_sizes, int n_in,
                              void* d_out, int out_size, void* d_ws, size_t ws_size,
                              hipStream_t stream) {
    const float* x     = (const float*)d_in[0];
    const int*   ei    = (const int*)  d_in[1];   // [2, E]: row 0 = src, row 1 = dst
    const float* W_gcn = (const float*)d_in[2];
    const float* b_gcn = (const float*)d_in[3];
    const float* W_lin = (const float*)d_in[4];
    const float* b_lin = (const float*)d_in[5];
    float* out = (float*)d_out;

    // workspace: g[N*128] | col[E] | row_ptr[N+1] | degi[N] | dinv[N] | partial[512]
    // packed (int[E], 12.8 MB) aliases g (51.2 MB) — consumed by fill before gemm writes g.
    float* g       = (float*)d_ws;
    int*   col     = (int*)(g + (size_t)N_NODES * HID_DIM);
    int*   row_ptr = col + N_EDGES;
    int*   degi    = row_ptr + (N_NODES + 1);
    float* dinv    = (float*)(degi + N_NODES);
    int*   partial = (int*)(dinv + N_NODES);
    int*   packed  = (int*)g;

    hipMemsetAsync(degi, 0, N_NODES * sizeof(int), stream);

    deg_rank_kernel<<<(N_EDGES + 255) / 256, 256, 0, stream>>>(ei, degi, packed);
    blocksum_kernel<<<NB_SCAN, 256, 0, stream>>>(degi, partial);
    scan_partial_kernel<<<1, 512, 0, stream>>>(partial);
    writeptr_kernel<<<NB_SCAN, 256, 0, stream>>>(degi, partial, row_ptr, dinv);
    fill_pass_kernel<<<FP_PASSES * FP_BLOCKS_PER_PASS, 256, 0, stream>>>(
        ei + N_EDGES, packed, row_ptr, col);
    gemm_kernel<<<N_NODES / GEMM_NPB, 256, 0, stream>>>(x, W_gcn, dinv, g);   // overwrites packed
    gather_kernel<<<(N_NODES * 32 + 255) / 256, 256, 0, stream>>>(
        row_ptr, col, g, dinv, b_gcn, W_lin, b_lin, out);
}

// Round 5
// 435.046 us; speedup vs baseline: 3.0518x; 1.2319x over previous
//
#include <hip/hip_runtime.h>
#include <hip/hip_fp16.h>

#define N_NODES 100000
#define N_EDGES 3200000
#define IN_DIM 64
#define HID_DIM 128
#define OUT_DIM 2
#define NB_SCAN 391   // ceil(N_NODES / 256)

#define FP_PASSES 4
#define FP_NODES_PER_PASS 25000          // 4 * 25000 = 100000 exact
#define FP_EPT 4                         // edges per thread (int4 load of dst)
#define FP_BLOCKS_PER_PASS (N_EDGES / (256 * FP_EPT))   // 3125 exact

// ---------------------------------------------------------------------------
// K1: degree histogram + per-edge rank capture. rank = old count for dst, so
// (row_ptr[d] + rank) is a unique slot — fill needs no atomics at all.
// packed = src | (rank << 17): src < 2^17, rank (max in-deg ~70) << 2^15.
__global__ __launch_bounds__(256) void deg_rank_kernel(const int* __restrict__ ei,
                                                       int* __restrict__ degi,
                                                       int* __restrict__ packed) {
    int e = blockIdx.x * 256 + threadIdx.x;
    if (e < N_EDGES) {
        const int s = ei[e];
        const int d = ei[N_EDGES + e];
        const int r = atomicAdd(&degi[d], 1);   // 100k counters: ~32/addr contention, L2-resident
        packed[e] = s | (r << 17);              // sequential write
    }
}

// K2: per-256-block sums of degi -> partial[NB_SCAN]
__global__ __launch_bounds__(256) void blocksum_kernel(const int* __restrict__ degi,
                                                       int* __restrict__ partial) {
    __shared__ int s[256];
    const int tid = threadIdx.x;
    const int i = blockIdx.x * 256 + tid;
    s[tid] = (i < N_NODES) ? degi[i] : 0;
    __syncthreads();
    #pragma unroll
    for (int off = 128; off > 0; off >>= 1) {
        if (tid < off) s[tid] += s[tid + off];
        __syncthreads();
    }
    if (tid == 0) partial[blockIdx.x] = s[0];
}

// K3: exclusive scan of partial[NB_SCAN] in one 512-thread block
__global__ __launch_bounds__(512) void scan_partial_kernel(int* __restrict__ partial) {
    __shared__ int s[512];
    const int tid = threadIdx.x;
    const int v = (tid < NB_SCAN) ? partial[tid] : 0;
    s[tid] = v;
    __syncthreads();
    for (int off = 1; off < 512; off <<= 1) {
        int t = (tid >= off) ? s[tid - off] : 0;
        __syncthreads();
        s[tid] += t;
        __syncthreads();
    }
    if (tid < NB_SCAN) partial[tid] = s[tid] - v;   // exclusive
}

// K4: local scan + block offset -> row_ptr; also dinv
__global__ __launch_bounds__(256) void writeptr_kernel(const int* __restrict__ degi,
                                                       const int* __restrict__ partial,
                                                       int* __restrict__ row_ptr,
                                                       float* __restrict__ dinv) {
    __shared__ int s[256];
    const int tid = threadIdx.x;
    const int i = blockIdx.x * 256 + tid;
    const int v = (i < N_NODES) ? degi[i] : 0;
    s[tid] = v;
    __syncthreads();
    for (int off = 1; off < 256; off <<= 1) {
        int t = (tid >= off) ? s[tid - off] : 0;
        __syncthreads();
        s[tid] += t;
        __syncthreads();
    }
    if (i < N_NODES) {
        const int start = partial[blockIdx.x] + s[tid] - v;   // exclusive global
        row_ptr[i] = start;
        dinv[i]    = rsqrtf((float)v + 1.0f);
        if (i == N_NODES - 1) row_ptr[N_NODES] = start + v;
    }
}

// K5: atomic-free CSR fill, partitioned into FP_PASSES dst-range passes for
// write locality. Pass p writes only dst in [25000p, 25000(p+1)) -> col window
// ~3.2 MB, L2-resident. Slots disjoint by construction.
__global__ __launch_bounds__(256) void fill_pass_kernel(const int* __restrict__ dst,
                                                        const int* __restrict__ packed,
                                                        const int* __restrict__ row_ptr,
                                                        int* __restrict__ col) {
    const int p  = blockIdx.x / FP_BLOCKS_PER_PASS;
    const int b  = blockIdx.x % FP_BLOCKS_PER_PASS;
    const int lo = p * FP_NODES_PER_PASS;
    const int hi = lo + FP_NODES_PER_PASS;
    const int e0 = (b * 256 + threadIdx.x) * FP_EPT;
    const int4 d4 = *(const int4*)(dst + e0);
    const int dd[4] = {d4.x, d4.y, d4.z, d4.w};
    #pragma unroll
    for (int i = 0; i < FP_EPT; ++i) {
        const int d = dd[i];
        if (d >= lo && d < hi) {
            const int pk = packed[e0 + i];
            col[row_ptr[d] + (pk >> 17)] = pk & 0x1FFFF;
        }
    }
}

// K6: g = fp16( (x @ W_gcn) * dinv[row] ).  W (64x128 = 32KB) staged in LDS.
// Output layout: g_h[node*128 + col] as __half; thread jq writes cols 4jq..4jq+3 (8 B).
#define GEMM_NPB 8
__global__ __launch_bounds__(256) void gemm_kernel(const float* __restrict__ x,
                                                   const float* __restrict__ W,
                                                   const float* __restrict__ dinv,
                                                   __half* __restrict__ g_h) {
    __shared__ float4 Ws[IN_DIM * HID_DIM / 4];       // 32 KB
    __shared__ float  xs[GEMM_NPB * IN_DIM];          // 2 KB
    const int tid = threadIdx.x;

    const float4* W4 = (const float4*)W;
    #pragma unroll
    for (int i = tid; i < IN_DIM * HID_DIM / 4; i += 256) Ws[i] = W4[i];

    const int node0 = blockIdx.x * GEMM_NPB;
    const float4* x4 = (const float4*)(x + (size_t)node0 * IN_DIM);
    for (int i = tid; i < GEMM_NPB * IN_DIM / 4; i += 256) ((float4*)xs)[i] = x4[i];
    __syncthreads();

    const int jq = tid & 31;
    const int nl = tid >> 5;
    const float* xrow = xs + nl * IN_DIM;

    float4 acc = {0.f, 0.f, 0.f, 0.f};
    #pragma unroll
    for (int k = 0; k < IN_DIM; ++k) {
        const float  xv = xrow[k];
        const float4 wv = Ws[k * 32 + jq];
        acc.x += xv * wv.x; acc.y += xv * wv.y;
        acc.z += xv * wv.z; acc.w += xv * wv.w;
    }
    const int node = node0 + nl;
    const float dv = dinv[node];
    __half2 h0 = __floats2half2_rn(acc.x * dv, acc.y * dv);
    __half2 h1 = __floats2half2_rn(acc.z * dv, acc.w * dv);
    uint2 pk;
    pk.x = *(unsigned int*)&h0;
    pk.y = *(unsigned int*)&h1;
    ((uint2*)g_h)[(size_t)node * 32 + jq] = pk;
}

// K7: fused gather + epilogue. 16 lanes per node; lane l holds 8 fp16 cols
// 8l..8l+7 (one 16 B uint4 load per neighbor per lane -> 256 B/edge group).
__global__ __launch_bounds__(256) void gather_kernel(const int* __restrict__ row_ptr,
                                                     const int* __restrict__ col,
                                                     const __half* __restrict__ g_h,
                                                     const float* __restrict__ dinv,
                                                     const float* __restrict__ b_gcn,
                                                     const float* __restrict__ W_lin,
                                                     const float* __restrict__ b_lin,
                                                     float* __restrict__ out) {
    const int t    = blockIdx.x * 256 + threadIdx.x;
    const int n    = t >> 4;
    const int lane = t & 15;
    if (n >= N_NODES) return;

    const uint4* g16 = (const uint4*)g_h;   // 8 halves per uint4; 16 per node row

    float accf[8];
    {
        const uint4 pk = g16[(size_t)n * 16 + lane];   // self-loop message
        const __half2* h = (const __half2*)&pk;
        #pragma unroll
        for (int q = 0; q < 4; ++q) {
            const float2 f = __half22float2(h[q]);
            accf[2*q]   = f.x;
            accf[2*q+1] = f.y;
        }
    }

    const int beg = row_ptr[n];
    const int end = row_ptr[n + 1];

    for (int k = beg; k < end; k += 16) {
        const int m = end - k;
        const int sc = (lane < m) ? col[k + lane] : 0;   // 16 cols, coalesced
        const int lim = m < 16 ? m : 16;
        for (int j = 0; j < lim; ++j) {
            const int s = __shfl(sc, j, 16);
            const uint4 pk = g16[(size_t)s * 16 + lane]; // 256 B coalesced per group
            const __half2* h = (const __half2*)&pk;
            #pragma unroll
            for (int q = 0; q < 4; ++q) {
                const float2 f = __half22float2(h[q]);
                accf[2*q]   += f.x;
                accf[2*q+1] += f.y;
            }
        }
    }

    const float dv = dinv[n];
    const float4 bg0 = ((const float4*)b_gcn)[lane * 2];
    const float4 bg1 = ((const float4*)b_gcn)[lane * 2 + 1];
    const float bg[8] = {bg0.x, bg0.y, bg0.z, bg0.w, bg1.x, bg1.y, bg1.z, bg1.w};

    float o0 = 0.f, o1 = 0.f;
    const int c0 = lane * 8;
    #pragma unroll
    for (int q = 0; q < 8; ++q) {
        const float v = fmaxf(accf[q] * dv + bg[q], 0.f);
        o0 += v * W_lin[(c0 + q) * 2];
        o1 += v * W_lin[(c0 + q) * 2 + 1];
    }

    #pragma unroll
    for (int off = 8; off > 0; off >>= 1) {
        o0 += __shfl_down(o0, off, 16);
        o1 += __shfl_down(o1, off, 16);
    }
    if (lane == 0) {
        out[(size_t)n * 2 + 0] = o0 + b_lin[0];
        out[(size_t)n * 2 + 1] = o1 + b_lin[1];
    }
}

extern "C" void kernel_launch(void* const* d_in, const int* in_sizes, int n_in,
                              void* d_out, int out_size, void* d_ws, size_t ws_size,
                              hipStream_t stream) {
    const float* x     = (const float*)d_in[0];
    const int*   ei    = (const int*)  d_in[1];   // [2, E]: row 0 = src, row 1 = dst
    const float* W_gcn = (const float*)d_in[2];
    const float* b_gcn = (const float*)d_in[3];
    const float* W_lin = (const float*)d_in[4];
    const float* b_lin = (const float*)d_in[5];
    float* out = (float*)d_out;

    // workspace: g_h[N*128 halves, 25.6 MB] | col[E] | row_ptr[N+1] | degi[N] | dinv[N] | partial[512]
    // packed (int[E], 12.8 MB) aliases g_h region — consumed by fill before gemm writes g_h.
    __half* g_h    = (__half*)d_ws;
    int*   col     = (int*)(g_h + (size_t)N_NODES * HID_DIM);
    int*   row_ptr = col + N_EDGES;
    int*   degi    = row_ptr + (N_NODES + 1);
    float* dinv    = (float*)(degi + N_NODES);
    int*   partial = (int*)(dinv + N_NODES);
    int*   packed  = (int*)g_h;

    hipMemsetAsync(degi, 0, N_NODES * sizeof(int), stream);

    deg_rank_kernel<<<(N_EDGES + 255) / 256, 256, 0, stream>>>(ei, degi, packed);
    blocksum_kernel<<<NB_SCAN, 256, 0, stream>>>(degi, partial);
    scan_partial_kernel<<<1, 512, 0, stream>>>(partial);
    writeptr_kernel<<<NB_SCAN, 256, 0, stream>>>(degi, partial, row_ptr, dinv);
    fill_pass_kernel<<<FP_PASSES * FP_BLOCKS_PER_PASS, 256, 0, stream>>>(
        ei + N_EDGES, packed, row_ptr, col);
    gemm_kernel<<<N_NODES / GEMM_NPB, 256, 0, stream>>>(x, W_gcn, dinv, g_h);  // overwrites packed
    gather_kernel<<<(N_NODES * 16 + 255) / 256, 256, 0, stream>>>(
        row_ptr, col, g_h, dinv, b_gcn, W_lin, b_lin, out);
}

// Round 6
// 341.711 us; speedup vs baseline: 3.8854x; 1.2731x over previous
//
#include <hip/hip_runtime.h>
#include <hip/hip_fp16.h>

#define N_NODES 100000
#define N_EDGES 3200000
#define IN_DIM 64
#define HID_DIM 128
#define OUT_DIM 2
#define NB_SCAN 391            // ceil(N_NODES / 256)

#define NPASS 8                // dst-range passes
#define NPP 12500              // nodes per pass (50 KB LDS histogram)
#define NCHUNK 64              // edge chunks (blocks per pass)
#define C_I4 (N_EDGES / NCHUNK / 4)   // int4s per chunk = 12500

// ---------------------------------------------------------------------------
// K1: LDS-privatized degree histogram. Block (p,b): pass p (dst range), edge
// chunk b. Zero global atomics — LDS atomicAdd only, then sequential dump.
__global__ __launch_bounds__(256) void hist_kernel(const int* __restrict__ dst,
                                                   int* __restrict__ cnt) {
    __shared__ int h[NPP];
    const int p  = blockIdx.x >> 6;
    const int b  = blockIdx.x & 63;
    const int lo = p * NPP;
    const int tid = threadIdx.x;

    for (int i = tid; i < NPP; i += 256) h[i] = 0;
    __syncthreads();

    const int4* d4 = ((const int4*)dst) + b * C_I4;
    for (int i = tid; i < C_I4; i += 256) {
        const int4 v = d4[i];
        const int dd[4] = {v.x, v.y, v.z, v.w};
        #pragma unroll
        for (int k = 0; k < 4; ++k) {
            const int j = dd[k] - lo;
            if ((unsigned)j < NPP) atomicAdd(&h[j], 1);
        }
    }
    __syncthreads();
    int* outp = cnt + (size_t)blockIdx.x * NPP;
    for (int i = tid; i < NPP; i += 256) outp[i] = h[i];
}

// K2: degi[d] = sum_b cnt[p(d)][b][d]  +  per-256-block sums -> partial
__global__ __launch_bounds__(256) void reduce_blocksum_kernel(const int* __restrict__ cnt,
                                                              int* __restrict__ degi,
                                                              int* __restrict__ partial) {
    __shared__ int s[256];
    const int tid = threadIdx.x;
    const int d = blockIdx.x * 256 + tid;
    int deg = 0;
    if (d < N_NODES) {
        const int p = d / NPP;
        const int j = d - p * NPP;
        const int* base = cnt + (size_t)p * NCHUNK * NPP + j;
        #pragma unroll 8
        for (int b = 0; b < NCHUNK; ++b) deg += base[(size_t)b * NPP];
        degi[d] = deg;
    }
    s[tid] = deg;
    __syncthreads();
    #pragma unroll
    for (int off = 128; off > 0; off >>= 1) {
        if (tid < off) s[tid] += s[tid + off];
        __syncthreads();
    }
    if (tid == 0) partial[blockIdx.x] = s[0];
}

// K3: exclusive scan of partial[NB_SCAN] in one 512-thread block
__global__ __launch_bounds__(512) void scan_partial_kernel(int* __restrict__ partial) {
    __shared__ int s[512];
    const int tid = threadIdx.x;
    const int v = (tid < NB_SCAN) ? partial[tid] : 0;
    s[tid] = v;
    __syncthreads();
    for (int off = 1; off < 512; off <<= 1) {
        int t = (tid >= off) ? s[tid - off] : 0;
        __syncthreads();
        s[tid] += t;
        __syncthreads();
    }
    if (tid < NB_SCAN) partial[tid] = s[tid] - v;   // exclusive
}

// K4: local scan + block offset -> row_ptr; also dinv
__global__ __launch_bounds__(256) void writeptr_kernel(const int* __restrict__ degi,
                                                       const int* __restrict__ partial,
                                                       int* __restrict__ row_ptr,
                                                       float* __restrict__ dinv) {
    __shared__ int s[256];
    const int tid = threadIdx.x;
    const int i = blockIdx.x * 256 + tid;
    const int v = (i < N_NODES) ? degi[i] : 0;
    s[tid] = v;
    __syncthreads();
    for (int off = 1; off < 256; off <<= 1) {
        int t = (tid >= off) ? s[tid - off] : 0;
        __syncthreads();
        s[tid] += t;
        __syncthreads();
    }
    if (i < N_NODES) {
        const int start = partial[blockIdx.x] + s[tid] - v;   // exclusive global
        row_ptr[i] = start;
        dinv[i]    = rsqrtf((float)v + 1.0f);
        if (i == N_NODES - 1) row_ptr[N_NODES] = start + v;
    }
}

// K5: per-(block,node) cursor bases: exclusive scan of cnt across b, seeded
// with row_ptr[d]. In place (cnt becomes base). Coalesced across adjacent d.
__global__ __launch_bounds__(256) void base_kernel(const int* __restrict__ row_ptr,
                                                   int* __restrict__ cnt) {
    const int d = blockIdx.x * 256 + threadIdx.x;
    if (d >= N_NODES) return;
    const int p = d / NPP;
    const int j = d - p * NPP;
    int* base = cnt + (size_t)p * NCHUNK * NPP + j;
    int running = row_ptr[d];
    #pragma unroll 8
    for (int b = 0; b < NCHUNK; ++b) {
        const int t = base[(size_t)b * NPP];
        base[(size_t)b * NPP] = running;
        running += t;
    }
}

// K6: atomic-free-global CSR fill. Block (p,b) loads its cursor bases into
// LDS, streams its chunk (src/dst mostly L3-hit), LDS-atomic slot assignment.
// Slots disjoint across blocks by construction of base.
__global__ __launch_bounds__(256) void fill_kernel(const int* __restrict__ src,
                                                   const int* __restrict__ dst,
                                                   const int* __restrict__ cnt,
                                                   int* __restrict__ col) {
    __shared__ int cur[NPP];
    const int p  = blockIdx.x >> 6;
    const int b  = blockIdx.x & 63;
    const int lo = p * NPP;
    const int tid = threadIdx.x;

    const int* inp = cnt + (size_t)blockIdx.x * NPP;
    for (int i = tid; i < NPP; i += 256) cur[i] = inp[i];
    __syncthreads();

    const int4* d4 = ((const int4*)dst) + b * C_I4;
    const int4* s4 = ((const int4*)src) + b * C_I4;
    for (int i = tid; i < C_I4; i += 256) {
        const int4 dv = d4[i];
        const int4 sv = s4[i];
        const int dd[4] = {dv.x, dv.y, dv.z, dv.w};
        const int ss[4] = {sv.x, sv.y, sv.z, sv.w};
        #pragma unroll
        for (int k = 0; k < 4; ++k) {
            const int j = dd[k] - lo;
            if ((unsigned)j < NPP) {
                const int slot = atomicAdd(&cur[j], 1);
                col[slot] = ss[k];
            }
        }
    }
}

// K7: g = fp16( (x @ W_gcn) * dinv[row] ).  W (64x128 = 32KB) staged in LDS.
#define GEMM_NPB 8
__global__ __launch_bounds__(256) void gemm_kernel(const float* __restrict__ x,
                                                   const float* __restrict__ W,
                                                   const float* __restrict__ dinv,
                                                   __half* __restrict__ g_h) {
    __shared__ float4 Ws[IN_DIM * HID_DIM / 4];       // 32 KB
    __shared__ float  xs[GEMM_NPB * IN_DIM];          // 2 KB
    const int tid = threadIdx.x;

    const float4* W4 = (const float4*)W;
    #pragma unroll
    for (int i = tid; i < IN_DIM * HID_DIM / 4; i += 256) Ws[i] = W4[i];

    const int node0 = blockIdx.x * GEMM_NPB;
    const float4* x4 = (const float4*)(x + (size_t)node0 * IN_DIM);
    for (int i = tid; i < GEMM_NPB * IN_DIM / 4; i += 256) ((float4*)xs)[i] = x4[i];
    __syncthreads();

    const int jq = tid & 31;
    const int nl = tid >> 5;
    const float* xrow = xs + nl * IN_DIM;

    float4 acc = {0.f, 0.f, 0.f, 0.f};
    #pragma unroll
    for (int k = 0; k < IN_DIM; ++k) {
        const float  xv = xrow[k];
        const float4 wv = Ws[k * 32 + jq];
        acc.x += xv * wv.x; acc.y += xv * wv.y;
        acc.z += xv * wv.z; acc.w += xv * wv.w;
    }
    const int node = node0 + nl;
    const float dv = dinv[node];
    __half2 h0 = __floats2half2_rn(acc.x * dv, acc.y * dv);
    __half2 h1 = __floats2half2_rn(acc.z * dv, acc.w * dv);
    uint2 pk;
    pk.x = *(unsigned int*)&h0;
    pk.y = *(unsigned int*)&h1;
    ((uint2*)g_h)[(size_t)node * 32 + jq] = pk;
}

// K8: fused gather + epilogue. 16 lanes per node; lane l holds 8 fp16 cols.
__global__ __launch_bounds__(256) void gather_kernel(const int* __restrict__ row_ptr,
                                                     const int* __restrict__ col,
                                                     const __half* __restrict__ g_h,
                                                     const float* __restrict__ dinv,
                                                     const float* __restrict__ b_gcn,
                                                     const float* __restrict__ W_lin,
                                                     const float* __restrict__ b_lin,
                                                     float* __restrict__ out) {
    const int t    = blockIdx.x * 256 + threadIdx.x;
    const int n    = t >> 4;
    const int lane = t & 15;
    if (n >= N_NODES) return;

    const uint4* g16 = (const uint4*)g_h;

    float accf[8];
    {
        const uint4 pk = g16[(size_t)n * 16 + lane];   // self-loop message
        const __half2* h = (const __half2*)&pk;
        #pragma unroll
        for (int q = 0; q < 4; ++q) {
            const float2 f = __half22float2(h[q]);
            accf[2*q]   = f.x;
            accf[2*q+1] = f.y;
        }
    }

    const int beg = row_ptr[n];
    const int end = row_ptr[n + 1];

    for (int k = beg; k < end; k += 16) {
        const int m = end - k;
        const int sc = (lane < m) ? col[k + lane] : 0;
        const int lim = m < 16 ? m : 16;
        for (int j = 0; j < lim; ++j) {
            const int s = __shfl(sc, j, 16);
            const uint4 pk = g16[(size_t)s * 16 + lane];
            const __half2* h = (const __half2*)&pk;
            #pragma unroll
            for (int q = 0; q < 4; ++q) {
                const float2 f = __half22float2(h[q]);
                accf[2*q]   += f.x;
                accf[2*q+1] += f.y;
            }
        }
    }

    const float dv = dinv[n];
    const float4 bg0 = ((const float4*)b_gcn)[lane * 2];
    const float4 bg1 = ((const float4*)b_gcn)[lane * 2 + 1];
    const float bg[8] = {bg0.x, bg0.y, bg0.z, bg0.w, bg1.x, bg1.y, bg1.z, bg1.w};

    float o0 = 0.f, o1 = 0.f;
    const int c0 = lane * 8;
    #pragma unroll
    for (int q = 0; q < 8; ++q) {
        const float v = fmaxf(accf[q] * dv + bg[q], 0.f);
        o0 += v * W_lin[(c0 + q) * 2];
        o1 += v * W_lin[(c0 + q) * 2 + 1];
    }

    #pragma unroll
    for (int off = 8; off > 0; off >>= 1) {
        o0 += __shfl_down(o0, off, 16);
        o1 += __shfl_down(o1, off, 16);
    }
    if (lane == 0) {
        out[(size_t)n * 2 + 0] = o0 + b_lin[0];
        out[(size_t)n * 2 + 1] = o1 + b_lin[1];
    }
}

extern "C" void kernel_launch(void* const* d_in, const int* in_sizes, int n_in,
                              void* d_out, int out_size, void* d_ws, size_t ws_size,
                              hipStream_t stream) {
    const float* x     = (const float*)d_in[0];
    const int*   ei    = (const int*)  d_in[1];   // [2, E]: row 0 = src, row 1 = dst
    const float* W_gcn = (const float*)d_in[2];
    const float* b_gcn = (const float*)d_in[3];
    const float* W_lin = (const float*)d_in[4];
    const float* b_lin = (const float*)d_in[5];
    float* out = (float*)d_out;

    // workspace: union{ g_h[N*128 halves] , cnt[NPASS*NCHUNK*NPP ints] } (both
    // 25.6 MB; cnt consumed by fill before gemm writes g_h) | col[E] |
    // row_ptr[N+1] | degi[N] | dinv[N] | partial[512]
    __half* g_h    = (__half*)d_ws;
    int*    cnt    = (int*)d_ws;
    int*   col     = (int*)(g_h + (size_t)N_NODES * HID_DIM);
    int*   row_ptr = col + N_EDGES;
    int*   degi    = row_ptr + (N_NODES + 1);
    float* dinv    = (float*)(degi + N_NODES);
    int*   partial = (int*)(dinv + N_NODES);

    const int* src = ei;
    const int* dst = ei + N_EDGES;

    hist_kernel<<<NPASS * NCHUNK, 256, 0, stream>>>(dst, cnt);
    reduce_blocksum_kernel<<<NB_SCAN, 256, 0, stream>>>(cnt, degi, partial);
    scan_partial_kernel<<<1, 512, 0, stream>>>(partial);
    writeptr_kernel<<<NB_SCAN, 256, 0, stream>>>(degi, partial, row_ptr, dinv);
    base_kernel<<<NB_SCAN, 256, 0, stream>>>(row_ptr, cnt);
    fill_kernel<<<NPASS * NCHUNK, 256, 0, stream>>>(src, dst, cnt, col);
    gemm_kernel<<<N_NODES / GEMM_NPB, 256, 0, stream>>>(x, W_gcn, dinv, g_h);  // overwrites cnt
    gather_kernel<<<(N_NODES * 16 + 255) / 256, 256, 0, stream>>>(
        row_ptr, col, g_h, dinv, b_gcn, W_lin, b_lin, out);
}

// Round 7
// 319.316 us; speedup vs baseline: 4.1579x; 1.0701x over previous
//
#include <hip/hip_runtime.h>
#include <hip/hip_fp16.h>

#define N_NODES 100000
#define N_EDGES 3200000
#define IN_DIM 64
#define HID_DIM 128
#define NB_SCAN 391            // ceil(N_NODES / 256)

#define NCHUNK 64              // edge chunks (K1 blocks)
#define CHUNK (N_EDGES / NCHUNK)       // 50000 edges per chunk
#define NPASS 8                // fill dst-range passes
#define NPP 12500              // nodes per fill pass (50 KB LDS int cursors)
#define TILE_CAP 8192          // per-(pass,chunk) tile capacity: mean 6250, sigma 74
#define NWORDS 25000           // byte-hist words (4 nodes per word, 100 KB LDS)

// ---------------------------------------------------------------------------
// K1: single-pass byte-packed LDS degree histogram (all 100k nodes in 100 KB)
// fused with edge partition into (pass, chunk) tiles. Zero global atomics.
// packed tile entry = src | (dloc << 17): src < 2^17, dloc < 12500 < 2^14.
__global__ __launch_bounds__(1024) void hist_part_kernel(const int* __restrict__ src,
                                                         const int* __restrict__ dst,
                                                         int* __restrict__ cnt4,
                                                         int* __restrict__ tmp,
                                                         int* __restrict__ tile_cnt) {
    __shared__ int h4[NWORDS];          // 100 KB byte counters
    __shared__ int tcur[NPASS];
    const int b = blockIdx.x;
    const int tid = threadIdx.x;

    for (int i = tid; i < NWORDS; i += 1024) h4[i] = 0;
    if (tid < NPASS) tcur[tid] = 0;
    __syncthreads();

    const int e0 = b * CHUNK;
    for (int i = tid; i < CHUNK; i += 1024) {
        const int d = dst[e0 + i];
        const int s = src[e0 + i];
        atomicAdd(&h4[d >> 2], 1 << ((d & 3) * 8));   // byte counter, max ~10 per chunk
        const int p = d / NPP;                         // magic-mul div
        const int dloc = d - p * NPP;
        const int pos = atomicAdd(&tcur[p], 1);        // LDS, 8 addrs
        tmp[(size_t)(p * NCHUNK + b) * TILE_CAP + pos] = s | (dloc << 17);
    }
    __syncthreads();

    int* outp = cnt4 + (size_t)b * NWORDS;
    for (int i = tid; i < NWORDS; i += 1024) outp[i] = h4[i];
    if (tid < NPASS) tile_cnt[tid * NCHUNK + b] = tcur[tid];
}

// K2: degi[d] = sum_b cnt byte + per-256-block sums -> partial
__global__ __launch_bounds__(256) void reduce_blocksum_kernel(const int* __restrict__ cnt4,
                                                              int* __restrict__ degi,
                                                              int* __restrict__ partial) {
    __shared__ int s[256];
    const int tid = threadIdx.x;
    const int d = blockIdx.x * 256 + tid;
    int deg = 0;
    if (d < N_NODES) {
        const int w = d >> 2, sh = (d & 3) * 8;
        #pragma unroll 8
        for (int b = 0; b < NCHUNK; ++b)
            deg += (cnt4[(size_t)b * NWORDS + w] >> sh) & 255;
        degi[d] = deg;
    }
    s[tid] = deg;
    __syncthreads();
    #pragma unroll
    for (int off = 128; off > 0; off >>= 1) {
        if (tid < off) s[tid] += s[tid + off];
        __syncthreads();
    }
    if (tid == 0) partial[blockIdx.x] = s[0];
}

// K3: exclusive scan of partial[NB_SCAN]
__global__ __launch_bounds__(512) void scan_partial_kernel(int* __restrict__ partial) {
    __shared__ int s[512];
    const int tid = threadIdx.x;
    const int v = (tid < NB_SCAN) ? partial[tid] : 0;
    s[tid] = v;
    __syncthreads();
    for (int off = 1; off < 512; off <<= 1) {
        int t = (tid >= off) ? s[tid - off] : 0;
        __syncthreads();
        s[tid] += t;
        __syncthreads();
    }
    if (tid < NB_SCAN) partial[tid] = s[tid] - v;   // exclusive
}

// K4: local scan + block offset -> row_ptr; also dinv
__global__ __launch_bounds__(256) void writeptr_kernel(const int* __restrict__ degi,
                                                       const int* __restrict__ partial,
                                                       int* __restrict__ row_ptr,
                                                       float* __restrict__ dinv) {
    __shared__ int s[256];
    const int tid = threadIdx.x;
    const int i = blockIdx.x * 256 + tid;
    const int v = (i < N_NODES) ? degi[i] : 0;
    s[tid] = v;
    __syncthreads();
    for (int off = 1; off < 256; off <<= 1) {
        int t = (tid >= off) ? s[tid - off] : 0;
        __syncthreads();
        s[tid] += t;
        __syncthreads();
    }
    if (i < N_NODES) {
        const int start = partial[blockIdx.x] + s[tid] - v;
        row_ptr[i] = start;
        dinv[i]    = rsqrtf((float)v + 1.0f);
        if (i == N_NODES - 1) row_ptr[N_NODES] = start + v;
    }
}

// K5: per-(chunk, node) cursor bases: base[(p*64+b)*NPP + dloc] =
// row_ptr[d] + sum_{b'<b} cnt[b'][d].  Coalesced across adjacent d.
__global__ __launch_bounds__(256) void base_kernel(const int* __restrict__ row_ptr,
                                                   const int* __restrict__ cnt4,
                                                   int* __restrict__ base) {
    const int d = blockIdx.x * 256 + threadIdx.x;
    if (d >= N_NODES) return;
    const int p = d / NPP;
    const int dloc = d - p * NPP;
    const int w = d >> 2, sh = (d & 3) * 8;
    int running = row_ptr[d];
    int* bp = base + (size_t)(p * NCHUNK) * NPP + dloc;
    #pragma unroll 8
    for (int b = 0; b < NCHUNK; ++b) {
        bp[(size_t)b * NPP] = running;
        running += (cnt4[(size_t)b * NWORDS + w] >> sh) & 255;
    }
}

// K6: CSR fill from pre-filtered tiles. Block (p,b): load its cursor bases,
// stream its tile (contiguous), LDS-atomic slot assign, write col.
__global__ __launch_bounds__(256) void fill_kernel(const int* __restrict__ tmp,
                                                   const int* __restrict__ tile_cnt,
                                                   const int* __restrict__ base,
                                                   int* __restrict__ col) {
    __shared__ int cur[NPP];            // 50 KB
    const int tid = threadIdx.x;
    const int* bp = base + (size_t)blockIdx.x * NPP;
    for (int i = tid; i < NPP; i += 256) cur[i] = bp[i];
    __syncthreads();

    const int n = tile_cnt[blockIdx.x];               // blockIdx.x == p*NCHUNK+b
    const int* t = tmp + (size_t)blockIdx.x * TILE_CAP;
    for (int i = tid; i < n; i += 256) {
        const int pk = t[i];
        const int slot = atomicAdd(&cur[pk >> 17], 1);
        col[slot] = pk & 0x1FFFF;
    }
}

// K7: g = fp16( (x @ W_gcn) * dinv[row] ).  W (64x128 = 32KB) staged in LDS.
#define GEMM_NPB 8
__global__ __launch_bounds__(256) void gemm_kernel(const float* __restrict__ x,
                                                   const float* __restrict__ W,
                                                   const float* __restrict__ dinv,
                                                   __half* __restrict__ g_h) {
    __shared__ float4 Ws[IN_DIM * HID_DIM / 4];       // 32 KB
    __shared__ float  xs[GEMM_NPB * IN_DIM];          // 2 KB
    const int tid = threadIdx.x;

    const float4* W4 = (const float4*)W;
    #pragma unroll
    for (int i = tid; i < IN_DIM * HID_DIM / 4; i += 256) Ws[i] = W4[i];

    const int node0 = blockIdx.x * GEMM_NPB;
    const float4* x4 = (const float4*)(x + (size_t)node0 * IN_DIM);
    for (int i = tid; i < GEMM_NPB * IN_DIM / 4; i += 256) ((float4*)xs)[i] = x4[i];
    __syncthreads();

    const int jq = tid & 31;
    const int nl = tid >> 5;
    const float* xrow = xs + nl * IN_DIM;

    float4 acc = {0.f, 0.f, 0.f, 0.f};
    #pragma unroll
    for (int k = 0; k < IN_DIM; ++k) {
        const float  xv = xrow[k];
        const float4 wv = Ws[k * 32 + jq];
        acc.x += xv * wv.x; acc.y += xv * wv.y;
        acc.z += xv * wv.z; acc.w += xv * wv.w;
    }
    const int node = node0 + nl;
    const float dv = dinv[node];
    __half2 h0 = __floats2half2_rn(acc.x * dv, acc.y * dv);
    __half2 h1 = __floats2half2_rn(acc.z * dv, acc.w * dv);
    uint2 pk;
    pk.x = *(unsigned int*)&h0;
    pk.y = *(unsigned int*)&h1;
    ((uint2*)g_h)[(size_t)node * 32 + jq] = pk;
}

// K8: fused gather + epilogue. 16 lanes per node; lane l holds 8 fp16 cols.
// Inner loop unrolled x4 -> 4 independent gathers in flight (was latency-bound
// at ~830 ns/edge with 1 outstanding load).
__global__ __launch_bounds__(256) void gather_kernel(const int* __restrict__ row_ptr,
                                                     const int* __restrict__ col,
                                                     const __half* __restrict__ g_h,
                                                     const float* __restrict__ dinv,
                                                     const float* __restrict__ b_gcn,
                                                     const float* __restrict__ W_lin,
                                                     const float* __restrict__ b_lin,
                                                     float* __restrict__ out) {
    const int t    = blockIdx.x * 256 + threadIdx.x;
    const int n    = t >> 4;
    const int lane = t & 15;
    if (n >= N_NODES) return;

    const uint4* g16 = (const uint4*)g_h;

    float accf[8];
    {
        const uint4 pk = g16[(size_t)n * 16 + lane];   // self-loop message
        const __half2* h = (const __half2*)&pk;
        #pragma unroll
        for (int q = 0; q < 4; ++q) {
            const float2 f = __half22float2(h[q]);
            accf[2*q]   = f.x;
            accf[2*q+1] = f.y;
        }
    }

    const int beg = row_ptr[n];
    const int end = row_ptr[n + 1];

    for (int k = beg; k < end; k += 16) {
        const int idx = k + lane;
        const int sc = (idx < end) ? col[idx] : 0;
        const int lim = (end - k) < 16 ? (end - k) : 16;
        int j = 0;
        for (; j + 4 <= lim; j += 4) {
            const int s0 = __shfl(sc, j,     16);
            const int s1 = __shfl(sc, j + 1, 16);
            const int s2 = __shfl(sc, j + 2, 16);
            const int s3 = __shfl(sc, j + 3, 16);
            const uint4 p0 = g16[(size_t)s0 * 16 + lane];
            const uint4 p1 = g16[(size_t)s1 * 16 + lane];
            const uint4 p2 = g16[(size_t)s2 * 16 + lane];
            const uint4 p3 = g16[(size_t)s3 * 16 + lane];
            const __half2* h0 = (const __half2*)&p0;
            const __half2* h1 = (const __half2*)&p1;
            const __half2* h2 = (const __half2*)&p2;
            const __half2* h3 = (const __half2*)&p3;
            #pragma unroll
            for (int q = 0; q < 4; ++q) {
                float2 f0 = __half22float2(h0[q]);
                float2 f1 = __half22float2(h1[q]);
                float2 f2 = __half22float2(h2[q]);
                float2 f3 = __half22float2(h3[q]);
                accf[2*q]   += (f0.x + f1.x) + (f2.x + f3.x);
                accf[2*q+1] += (f0.y + f1.y) + (f2.y + f3.y);
            }
        }
        for (; j < lim; ++j) {
            const int s = __shfl(sc, j, 16);
            const uint4 pk = g16[(size_t)s * 16 + lane];
            const __half2* h = (const __half2*)&pk;
            #pragma unroll
            for (int q = 0; q < 4; ++q) {
                const float2 f = __half22float2(h[q]);
                accf[2*q]   += f.x;
                accf[2*q+1] += f.y;
            }
        }
    }

    const float dv = dinv[n];
    const float4 bg0 = ((const float4*)b_gcn)[lane * 2];
    const float4 bg1 = ((const float4*)b_gcn)[lane * 2 + 1];
    const float bg[8] = {bg0.x, bg0.y, bg0.z, bg0.w, bg1.x, bg1.y, bg1.z, bg1.w};

    float o0 = 0.f, o1 = 0.f;
    const int c0 = lane * 8;
    #pragma unroll
    for (int q = 0; q < 8; ++q) {
        const float v = fmaxf(accf[q] * dv + bg[q], 0.f);
        o0 += v * W_lin[(c0 + q) * 2];
        o1 += v * W_lin[(c0 + q) * 2 + 1];
    }

    #pragma unroll
    for (int off = 8; off > 0; off >>= 1) {
        o0 += __shfl_down(o0, off, 16);
        o1 += __shfl_down(o1, off, 16);
    }
    if (lane == 0) {
        out[(size_t)n * 2 + 0] = o0 + b_lin[0];
        out[(size_t)n * 2 + 1] = o1 + b_lin[1];
    }
}

extern "C" void kernel_launch(void* const* d_in, const int* in_sizes, int n_in,
                              void* d_out, int out_size, void* d_ws, size_t ws_size,
                              hipStream_t stream) {
    const float* x     = (const float*)d_in[0];
    const int*   ei    = (const int*)  d_in[1];   // [2, E]: row 0 = src, row 1 = dst
    const float* W_gcn = (const float*)d_in[2];
    const float* b_gcn = (const float*)d_in[3];
    const float* W_lin = (const float*)d_in[4];
    const float* b_lin = (const float*)d_in[5];
    float* out = (float*)d_out;

    // Region A (48.8 MB): [cnt4 6.4 MB][tmp 16.8 MB][base 25.6 MB] — all dead
    // after fill (K6). g_h (25.6 MB) aliases the front of A, written by gemm (K7).
    // Then: col[E] | row_ptr[N+1] | degi[N] | dinv[N] | partial[512] | tile_cnt[512]
    int*    cnt4    = (int*)d_ws;                         // 64*25000        = 1,600,000
    int*    tmp     = cnt4 + (size_t)NCHUNK * NWORDS;     // 512*8192        = 4,194,304
    int*    base    = tmp + (size_t)NPASS * NCHUNK * TILE_CAP;  // 512*12500 = 6,400,000
    int*    col     = base + (size_t)NPASS * NCHUNK * NPP;
    int*    row_ptr = col + N_EDGES;
    int*    degi    = row_ptr + (N_NODES + 1);
    float*  dinv    = (float*)(degi + N_NODES);
    int*    partial = (int*)(dinv + N_NODES);
    int*    tile_cnt= partial + 512;
    __half* g_h     = (__half*)d_ws;

    const int* src = ei;
    const int* dst = ei + N_EDGES;

    hist_part_kernel<<<NCHUNK, 1024, 0, stream>>>(src, dst, cnt4, tmp, tile_cnt);
    reduce_blocksum_kernel<<<NB_SCAN, 256, 0, stream>>>(cnt4, degi, partial);
    scan_partial_kernel<<<1, 512, 0, stream>>>(partial);
    writeptr_kernel<<<NB_SCAN, 256, 0, stream>>>(degi, partial, row_ptr, dinv);
    base_kernel<<<NB_SCAN, 256, 0, stream>>>(row_ptr, cnt4, base);
    fill_kernel<<<NPASS * NCHUNK, 256, 0, stream>>>(tmp, tile_cnt, base, col);
    gemm_kernel<<<N_NODES / GEMM_NPB, 256, 0, stream>>>(x, W_gcn, dinv, g_h);  // overwrites cnt4/tmp
    gather_kernel<<<(N_NODES * 16 + 255) / 256, 256, 0, stream>>>(
        row_ptr, col, g_h, dinv, b_gcn, W_lin, b_lin, out);
}

// Round 8
// 282.797 us; speedup vs baseline: 4.6948x; 1.1291x over previous
//
#include <hip/hip_runtime.h>
#include <hip/hip_fp16.h>

#define N_NODES 100000
#define N_EDGES 3200000
#define IN_DIM 64
#define HID_DIM 128
#define NB_SCAN 391            // ceil(N_NODES / 256)

#define NCHUNK 64              // edge chunks (K1 blocks)
#define CHUNK (N_EDGES / NCHUNK)       // 50000 edges per chunk
#define NPASS 8                // fill dst-range passes
#define NPP 12500              // nodes per fill pass (50 KB LDS int cursors)
#define TILE_CAP 8192          // per-(pass,chunk) tile capacity: mean 6250, sigma 74
#define NWORDS 25000           // byte-hist words (4 nodes per word, 100 KB LDS)

// ---------------------------------------------------------------------------
// K1: single-pass byte-packed LDS degree histogram fused with edge partition
// into (pass, chunk) tiles. Zero global atomics.
// packed tile entry = src | (dloc << 17): src < 2^17, dloc < 12500 < 2^14.
__global__ __launch_bounds__(1024) void hist_part_kernel(const int* __restrict__ src,
                                                         const int* __restrict__ dst,
                                                         int* __restrict__ cnt4,
                                                         int* __restrict__ tmp,
                                                         int* __restrict__ tile_cnt) {
    __shared__ int h4[NWORDS];          // 100 KB byte counters
    __shared__ int tcur[NPASS];
    const int b = blockIdx.x;
    const int tid = threadIdx.x;

    for (int i = tid; i < NWORDS; i += 1024) h4[i] = 0;
    if (tid < NPASS) tcur[tid] = 0;
    __syncthreads();

    const int e0 = b * CHUNK;
    for (int i = tid; i < CHUNK; i += 1024) {
        const int d = dst[e0 + i];
        const int s = src[e0 + i];
        atomicAdd(&h4[d >> 2], 1 << ((d & 3) * 8));   // byte counter, max ~10 per chunk
        const int p = d / NPP;
        const int dloc = d - p * NPP;
        const int pos = atomicAdd(&tcur[p], 1);        // LDS, 8 addrs
        tmp[(size_t)(p * NCHUNK + b) * TILE_CAP + pos] = s | (dloc << 17);
    }
    __syncthreads();

    int* outp = cnt4 + (size_t)b * NWORDS;
    for (int i = tid; i < NWORDS; i += 1024) outp[i] = h4[i];
    if (tid < NPASS) tile_cnt[tid * NCHUNK + b] = tcur[tid];
}

// K2: degi[d] = sum_b cnt byte; dinv = rsqrt(deg+1); block sums -> partial
__global__ __launch_bounds__(256) void reduce_blocksum_kernel(const int* __restrict__ cnt4,
                                                              int* __restrict__ degi,
                                                              float* __restrict__ dinv,
                                                              int* __restrict__ partial) {
    __shared__ int s[256];
    const int tid = threadIdx.x;
    const int d = blockIdx.x * 256 + tid;
    int deg = 0;
    if (d < N_NODES) {
        const int w = d >> 2, sh = (d & 3) * 8;
        #pragma unroll 8
        for (int b = 0; b < NCHUNK; ++b)
            deg += (cnt4[(size_t)b * NWORDS + w] >> sh) & 255;
        degi[d] = deg;
        dinv[d] = rsqrtf((float)deg + 1.0f);
    }
    s[tid] = deg;
    __syncthreads();
    #pragma unroll
    for (int off = 128; off > 0; off >>= 1) {
        if (tid < off) s[tid] += s[tid + off];
        __syncthreads();
    }
    if (tid == 0) partial[blockIdx.x] = s[0];
}

// K3: exclusive scan of partial[NB_SCAN]
__global__ __launch_bounds__(512) void scan_partial_kernel(int* __restrict__ partial) {
    __shared__ int s[512];
    const int tid = threadIdx.x;
    const int v = (tid < NB_SCAN) ? partial[tid] : 0;
    s[tid] = v;
    __syncthreads();
    for (int off = 1; off < 512; off <<= 1) {
        int t = (tid >= off) ? s[tid - off] : 0;
        __syncthreads();
        s[tid] += t;
        __syncthreads();
    }
    if (tid < NB_SCAN) partial[tid] = s[tid] - v;   // exclusive
}

// K4: local scan + block offset -> row_ptr
__global__ __launch_bounds__(256) void writeptr_kernel(const int* __restrict__ degi,
                                                       const int* __restrict__ partial,
                                                       int* __restrict__ row_ptr) {
    __shared__ int s[256];
    const int tid = threadIdx.x;
    const int i = blockIdx.x * 256 + tid;
    const int v = (i < N_NODES) ? degi[i] : 0;
    s[tid] = v;
    __syncthreads();
    for (int off = 1; off < 256; off <<= 1) {
        int t = (tid >= off) ? s[tid - off] : 0;
        __syncthreads();
        s[tid] += t;
        __syncthreads();
    }
    if (i < N_NODES) {
        const int start = partial[blockIdx.x] + s[tid] - v;
        row_ptr[i] = start;
        if (i == N_NODES - 1) row_ptr[N_NODES] = start + v;
    }
}

// K5: per-(chunk, node) cursor bases
__global__ __launch_bounds__(256) void base_kernel(const int* __restrict__ row_ptr,
                                                   const int* __restrict__ cnt4,
                                                   int* __restrict__ base) {
    const int d = blockIdx.x * 256 + threadIdx.x;
    if (d >= N_NODES) return;
    const int p = d / NPP;
    const int dloc = d - p * NPP;
    const int w = d >> 2, sh = (d & 3) * 8;
    int running = row_ptr[d];
    int* bp = base + (size_t)(p * NCHUNK) * NPP + dloc;
    #pragma unroll 8
    for (int b = 0; b < NCHUNK; ++b) {
        bp[(size_t)b * NPP] = running;
        running += (cnt4[(size_t)b * NWORDS + w] >> sh) & 255;
    }
}

// K6: CSR fill from pre-filtered tiles
__global__ __launch_bounds__(256) void fill_kernel(const int* __restrict__ tmp,
                                                   const int* __restrict__ tile_cnt,
                                                   const int* __restrict__ base,
                                                   int* __restrict__ col) {
    __shared__ int cur[NPP];            // 50 KB
    const int tid = threadIdx.x;
    const int* bp = base + (size_t)blockIdx.x * NPP;
    for (int i = tid; i < NPP; i += 256) cur[i] = bp[i];
    __syncthreads();

    const int n = tile_cnt[blockIdx.x];
    const int* t = tmp + (size_t)blockIdx.x * TILE_CAP;
    for (int i = tid; i < n; i += 256) {
        const int pk = t[i];
        const int slot = atomicAdd(&cur[pk >> 17], 1);
        col[slot] = pk & 0x1FFFF;
    }
}

// K7: y = fp16( x * dinv[row] ), 64 dims. Thread i -> 4 floats; node = i>>4.
__global__ __launch_bounds__(256) void scale_kernel(const float* __restrict__ x,
                                                    const float* __restrict__ dinv,
                                                    __half* __restrict__ y) {
    const int i = blockIdx.x * 256 + threadIdx.x;     // i < N*16
    const int node = i >> 4;
    const float dv = dinv[node];
    const float4 v = ((const float4*)x)[i];
    __half2 h0 = __floats2half2_rn(v.x * dv, v.y * dv);
    __half2 h1 = __floats2half2_rn(v.z * dv, v.w * dv);
    uint2 pk;
    pk.x = *(unsigned int*)&h0;
    pk.y = *(unsigned int*)&h1;
    ((uint2*)y)[i] = pk;
}

// K8: gather (64-dim): agg[d] = y[d] + sum_{s in CSR[d]} y[s], stored fp16.
// 8 lanes per node; lane l holds 8 fp16 dims 8l..8l+7 (one 16 B load/neighbor).
__global__ __launch_bounds__(256) void gather_kernel(const int* __restrict__ row_ptr,
                                                     const int* __restrict__ col,
                                                     const __half* __restrict__ y,
                                                     __half* __restrict__ agg) {
    const int t    = blockIdx.x * 256 + threadIdx.x;
    const int n    = t >> 3;
    const int lane = t & 7;
    if (n >= N_NODES) return;

    const uint4* y16 = (const uint4*)y;     // 8 halves per uint4; 8 per node row

    float accf[8];
    {
        const uint4 pk = y16[(size_t)n * 8 + lane];    // self-loop message
        const __half2* h = (const __half2*)&pk;
        #pragma unroll
        for (int q = 0; q < 4; ++q) {
            const float2 f = __half22float2(h[q]);
            accf[2*q]   = f.x;
            accf[2*q+1] = f.y;
        }
    }

    const int beg = row_ptr[n];
    const int end = row_ptr[n + 1];

    for (int k = beg; k < end; k += 8) {
        const int idx = k + lane;
        const int sc = (idx < end) ? col[idx] : 0;
        const int lim = (end - k) < 8 ? (end - k) : 8;
        int j = 0;
        for (; j + 4 <= lim; j += 4) {
            const int s0 = __shfl(sc, j,     8);
            const int s1 = __shfl(sc, j + 1, 8);
            const int s2 = __shfl(sc, j + 2, 8);
            const int s3 = __shfl(sc, j + 3, 8);
            const uint4 p0 = y16[(size_t)s0 * 8 + lane];
            const uint4 p1 = y16[(size_t)s1 * 8 + lane];
            const uint4 p2 = y16[(size_t)s2 * 8 + lane];
            const uint4 p3 = y16[(size_t)s3 * 8 + lane];
            const __half2* h0 = (const __half2*)&p0;
            const __half2* h1 = (const __half2*)&p1;
            const __half2* h2 = (const __half2*)&p2;
            const __half2* h3 = (const __half2*)&p3;
            #pragma unroll
            for (int q = 0; q < 4; ++q) {
                float2 f0 = __half22float2(h0[q]);
                float2 f1 = __half22float2(h1[q]);
                float2 f2 = __half22float2(h2[q]);
                float2 f3 = __half22float2(h3[q]);
                accf[2*q]   += (f0.x + f1.x) + (f2.x + f3.x);
                accf[2*q+1] += (f0.y + f1.y) + (f2.y + f3.y);
            }
        }
        for (; j < lim; ++j) {
            const int s = __shfl(sc, j, 8);
            const uint4 pk = y16[(size_t)s * 8 + lane];
            const __half2* h = (const __half2*)&pk;
            #pragma unroll
            for (int q = 0; q < 4; ++q) {
                const float2 f = __half22float2(h[q]);
                accf[2*q]   += f.x;
                accf[2*q+1] += f.y;
            }
        }
    }

    uint4 outpk;
    __half2* oh = (__half2*)&outpk;
    #pragma unroll
    for (int q = 0; q < 4; ++q)
        oh[q] = __floats2half2_rn(accf[2*q], accf[2*q+1]);
    ((uint4*)agg)[(size_t)n * 8 + lane] = outpk;
}

// K9: fused transform + relu + head:
// out[n] = relu( dinv[n]*agg[n] @ W_gcn + b_gcn ) @ W_lin + b_lin.
// 8 nodes/block; thread = (node_local nl, col-quad jq): cols 4jq..4jq+3.
#define H_NPB 8
__global__ __launch_bounds__(256) void head_kernel(const __half* __restrict__ agg,
                                                   const float* __restrict__ dinv,
                                                   const float* __restrict__ W,
                                                   const float* __restrict__ b_gcn,
                                                   const float* __restrict__ W_lin,
                                                   const float* __restrict__ b_lin,
                                                   float* __restrict__ out) {
    __shared__ float4 Ws[IN_DIM * HID_DIM / 4];       // 32 KB
    __shared__ float  as[H_NPB * IN_DIM];             // 2 KB
    const int tid = threadIdx.x;

    const float4* W4 = (const float4*)W;
    #pragma unroll
    for (int i = tid; i < IN_DIM * HID_DIM / 4; i += 256) Ws[i] = W4[i];

    const int node0 = blockIdx.x * H_NPB;
    // stage agg rows (fp16 -> fp32): 8*64 = 512 halves, 2 per thread
    {
        const __half2* a2 = (const __half2*)(agg + (size_t)node0 * IN_DIM);
        const float2 f = __half22float2(a2[tid]);
        as[tid * 2]     = f.x;
        as[tid * 2 + 1] = f.y;
    }
    __syncthreads();

    const int jq = tid & 31;
    const int nl = tid >> 5;
    const float* arow = as + nl * IN_DIM;
    const int node = node0 + nl;
    const float dv = dinv[node];

    float4 acc = {0.f, 0.f, 0.f, 0.f};
    #pragma unroll
    for (int k = 0; k < IN_DIM; ++k) {
        const float  av = arow[k];
        const float4 wv = Ws[k * 32 + jq];
        acc.x += av * wv.x; acc.y += av * wv.y;
        acc.z += av * wv.z; acc.w += av * wv.w;
    }

    const float4 bg = ((const float4*)b_gcn)[jq];
    float4 v;
    v.x = fmaxf(acc.x * dv + bg.x, 0.f);
    v.y = fmaxf(acc.y * dv + bg.y, 0.f);
    v.z = fmaxf(acc.z * dv + bg.z, 0.f);
    v.w = fmaxf(acc.w * dv + bg.w, 0.f);

    const int c = jq * 4;
    float o0 = v.x * W_lin[(c+0)*2]   + v.y * W_lin[(c+1)*2]
             + v.z * W_lin[(c+2)*2]   + v.w * W_lin[(c+3)*2];
    float o1 = v.x * W_lin[(c+0)*2+1] + v.y * W_lin[(c+1)*2+1]
             + v.z * W_lin[(c+2)*2+1] + v.w * W_lin[(c+3)*2+1];

    #pragma unroll
    for (int off = 16; off > 0; off >>= 1) {
        o0 += __shfl_down(o0, off, 32);
        o1 += __shfl_down(o1, off, 32);
    }
    if (jq == 0) {
        out[(size_t)node * 2 + 0] = o0 + b_lin[0];
        out[(size_t)node * 2 + 1] = o1 + b_lin[1];
    }
}

extern "C" void kernel_launch(void* const* d_in, const int* in_sizes, int n_in,
                              void* d_out, int out_size, void* d_ws, size_t ws_size,
                              hipStream_t stream) {
    const float* x     = (const float*)d_in[0];
    const int*   ei    = (const int*)  d_in[1];   // [2, E]: row 0 = src, row 1 = dst
    const float* W_gcn = (const float*)d_in[2];
    const float* b_gcn = (const float*)d_in[3];
    const float* W_lin = (const float*)d_in[4];
    const float* b_lin = (const float*)d_in[5];
    float* out = (float*)d_out;

    // Region A (48.8 MB): [cnt4 6.4 MB][tmp 16.8 MB][base 25.6 MB] — dead after
    // fill (K6). y (12.8 MB) + agg (12.8 MB) alias the front of A, written by
    // K7/K8 after fill. Then: col[E] | row_ptr[N+1] | degi[N] | dinv[N] |
    // partial[512] | tile_cnt[512]
    int*    cnt4    = (int*)d_ws;
    int*    tmp     = cnt4 + (size_t)NCHUNK * NWORDS;
    int*    base    = tmp + (size_t)NPASS * NCHUNK * TILE_CAP;
    int*    col     = base + (size_t)NPASS * NCHUNK * NPP;
    int*    row_ptr = col + N_EDGES;
    int*    degi    = row_ptr + (N_NODES + 1);
    float*  dinv    = (float*)(degi + N_NODES);
    int*    partial = (int*)(dinv + N_NODES);
    int*    tile_cnt= partial + 512;
    __half* y       = (__half*)d_ws;                          // N*64 halves
    __half* agg     = y + (size_t)N_NODES * IN_DIM;           // N*64 halves

    const int* src = ei;
    const int* dst = ei + N_EDGES;

    hist_part_kernel<<<NCHUNK, 1024, 0, stream>>>(src, dst, cnt4, tmp, tile_cnt);
    reduce_blocksum_kernel<<<NB_SCAN, 256, 0, stream>>>(cnt4, degi, dinv, partial);
    scan_partial_kernel<<<1, 512, 0, stream>>>(partial);
    writeptr_kernel<<<NB_SCAN, 256, 0, stream>>>(degi, partial, row_ptr);
    base_kernel<<<NB_SCAN, 256, 0, stream>>>(row_ptr, cnt4, base);
    fill_kernel<<<NPASS * NCHUNK, 256, 0, stream>>>(tmp, tile_cnt, base, col);
    scale_kernel<<<(N_NODES * 16) / 256 + 1, 256, 0, stream>>>(x, dinv, y);  // overwrites cnt4
    gather_kernel<<<(N_NODES * 8 + 255) / 256, 256, 0, stream>>>(row_ptr, col, y, agg);
    head_kernel<<<N_NODES / H_NPB, 256, 0, stream>>>(agg, dinv, W_gcn, b_gcn, W_lin, b_lin, out);
}